// Round 6
// baseline (4868.982 us; speedup 1.0000x reference)
//
#include <hip/hip_runtime.h>

#define HH  50   // hidden size
#define HP  64   // padded hidden (lanes)
#define RB  16   // batch elements per block
#define RBP 20   // padded batch dim (breaks 16-float bank stride, keeps 16B align)
#define TT  512  // timesteps
#define FF  4    // input features

__device__ __forceinline__ float sigm(float x)   { return 1.0f / (1.0f + __expf(-x)); }
__device__ __forceinline__ float tanh_f(float x) { return 1.0f - 2.0f / (1.0f + __expf(2.0f * x)); }
__device__ __forceinline__ float idf(float x)    { return x; }

// 8B-aligned float4 gather (weight rows are 200 B apart -> only 8 B aligned)
__device__ __forceinline__ float4 ld4u(const float* p) {
    const float2 a = *(const float2*)p;
    const float2 b = *(const float2*)(p + 2);
    return make_float4(a.x, a.y, b.x, b.y);
}

#define PIN4(V) asm volatile("" : "+v"((V).x), "+v"((V).y), "+v"((V).z), "+v"((V).w));
#define PIN2(V) asm volatile("" : "+v"((V).x), "+v"((V).y));

// One weight row (50 floats) as named values: 12 float4 + 1 float2.
#define DECLW(P, BASE) \
    float4 P##0  = ld4u((BASE) + 0);  float4 P##1  = ld4u((BASE) + 4);  \
    float4 P##2  = ld4u((BASE) + 8);  float4 P##3  = ld4u((BASE) + 12); \
    float4 P##4  = ld4u((BASE) + 16); float4 P##5  = ld4u((BASE) + 20); \
    float4 P##6  = ld4u((BASE) + 24); float4 P##7  = ld4u((BASE) + 28); \
    float4 P##8  = ld4u((BASE) + 32); float4 P##9  = ld4u((BASE) + 36); \
    float4 P##10 = ld4u((BASE) + 40); float4 P##11 = ld4u((BASE) + 44); \
    float2 P##t  = *(const float2*)((BASE) + 48);
#define PINW(P) \
    PIN4(P##0)  PIN4(P##1)  PIN4(P##2)  PIN4(P##3)  PIN4(P##4)  PIN4(P##5) \
    PIN4(P##6)  PIN4(P##7)  PIN4(P##8)  PIN4(P##9)  PIN4(P##10) PIN4(P##11) \
    PIN2(P##t)

// one j-step: broadcast 16 h-values (4x float4, RBP-padded row) + 16 FMA
#define JSTEP(W, PTR, J) { \
    const float4 ha = *(const float4*)((PTR) + (J) * RBP); \
    const float4 hb = *(const float4*)((PTR) + (J) * RBP + 4); \
    const float4 hc = *(const float4*)((PTR) + (J) * RBP + 8); \
    const float4 hd = *(const float4*)((PTR) + (J) * RBP + 12); \
    acc0  = fmaf((W), ha.x, acc0);  acc1  = fmaf((W), ha.y, acc1);  \
    acc2  = fmaf((W), ha.z, acc2);  acc3  = fmaf((W), ha.w, acc3);  \
    acc4  = fmaf((W), hb.x, acc4);  acc5  = fmaf((W), hb.y, acc5);  \
    acc6  = fmaf((W), hb.z, acc6);  acc7  = fmaf((W), hb.w, acc7);  \
    acc8  = fmaf((W), hc.x, acc8);  acc9  = fmaf((W), hc.y, acc9);  \
    acc10 = fmaf((W), hc.z, acc10); acc11 = fmaf((W), hc.w, acc11); \
    acc12 = fmaf((W), hd.x, acc12); acc13 = fmaf((W), hd.y, acc13); \
    acc14 = fmaf((W), hd.z, acc14); acc15 = fmaf((W), hd.w, acc15); }
#define JCHUNK(V, PTR, JB) \
    JSTEP((V).x, PTR, (JB)) JSTEP((V).y, PTR, (JB)+1) JSTEP((V).z, PTR, (JB)+2) JSTEP((V).w, PTR, (JB)+3)
#define JALL(P, PTR) \
    JCHUNK(P##0, PTR, 0)  JCHUNK(P##1, PTR, 4)   JCHUNK(P##2, PTR, 8)   JCHUNK(P##3, PTR, 12) \
    JCHUNK(P##4, PTR, 16) JCHUNK(P##5, PTR, 20)  JCHUNK(P##6, PTR, 24)  JCHUNK(P##7, PTR, 28) \
    JCHUNK(P##8, PTR, 32) JCHUNK(P##9, PTR, 36)  JCHUNK(P##10, PTR, 40) JCHUNK(P##11, PTR, 44) \
    JSTEP(P##t.x, PTR, 48) JSTEP(P##t.y, PTR, 49)

// store 16 accs (optionally activated) to EXCH[G][r][U], stride-1 lanes (conflict-free)
#define STORE16(EXCH, G, FN) \
    EXCH[G][0][U]  = FN(acc0);  EXCH[G][1][U]  = FN(acc1);  EXCH[G][2][U]  = FN(acc2);  EXCH[G][3][U]  = FN(acc3);  \
    EXCH[G][4][U]  = FN(acc4);  EXCH[G][5][U]  = FN(acc5);  EXCH[G][6][U]  = FN(acc6);  EXCH[G][7][U]  = FN(acc7);  \
    EXCH[G][8][U]  = FN(acc8);  EXCH[G][9][U]  = FN(acc9);  EXCH[G][10][U] = FN(acc10); EXCH[G][11][U] = FN(acc11); \
    EXCH[G][12][U] = FN(acc12); EXCH[G][13][U] = FN(acc13); EXCH[G][14][U] = FN(acc14); EXCH[G][15][U] = FN(acc15);

#define XINIT(R, A) { const float4 xv = xbufT[R][tm]; \
    A = fmaf(w0v.x, xv.x, fmaf(w0v.y, xv.y, fmaf(w0v.z, xv.z, fmaf(w0v.w, xv.w, bias0)))); }

// layer-0 elementwise for batch rb+RR (gates pre-activated in g0buf)
#define EW0(RR, CS) { const int r = rb + (RR); \
    const float gi = g0buf[0][r][U], gf = g0buf[1][r][U], gg = g0buf[2][r][U], go = g0buf[3][r][U]; \
    CS = fmaf(gf, CS, gi * gg); \
    h0buf[U][r] = go * tanh_f(CS); }

// layer-1 elementwise for batch rb+RR (raw partials in pIbuf/pHbuf)
#define EW1(RR, CS) { const int r = rb + (RR); \
    const float gi = sigm(pIbuf[0][r][U] + pHbuf[0][r][U] + bi); \
    const float gf = sigm(pIbuf[1][r][U] + pHbuf[1][r][U] + bf); \
    const float gg = tanh_f(pIbuf[2][r][U] + pHbuf[2][r][U] + bg); \
    const float go = sigm(pIbuf[3][r][U] + pHbuf[3][r][U] + bo); \
    CS = fmaf(gf, CS, gi * gg); \
    h1buf[U][r] = go * tanh_f(CS); }

__attribute__((amdgpu_waves_per_eu(3, 3)))
__launch_bounds__(768)
__global__ void lstm12_kernel(const float* __restrict__ x,
                              const float* __restrict__ Wih0, const float* __restrict__ Whh0,
                              const float* __restrict__ bih0, const float* __restrict__ bhh0,
                              const float* __restrict__ Wih1, const float* __restrict__ Whh1,
                              const float* __restrict__ bih1, const float* __restrict__ bhh1,
                              const float* __restrict__ fcW,  const float* __restrict__ fcb,
                              float* __restrict__ out)
{
    __shared__ __align__(16) float h0buf[HP][RBP];      // h0(t), [unit][batch]
    __shared__ __align__(16) float h1buf[HP][RBP];      // h1(t), [unit][batch]
    __shared__ float g0buf[4][RB][HP];                  // layer-0 activated gates
    __shared__ float pIbuf[4][RB][HP];                  // layer-1 Wih1*h0 partials
    __shared__ float pHbuf[4][RB][HP];                  // layer-1 Whh1*h1 partials
    __shared__ __align__(16) float4 xbufT[RB][64];      // x chunk, [batch][t]

    const int tid = threadIdx.x;
    const int w   = tid >> 6;           // 0-3: L0 gates | 4-7: L1-ih | 8-11: L1-hh
    const int U   = tid & 63;           // lane = hidden unit
    const int b0  = blockIdx.x * RB;
    const int Um  = (U < HH ? U : HH - 1);   // lanes >=50 duplicate row 49 (outputs unread)
    const int row = (w & 3) * HH + Um;       // gate row in [0,200)

    for (int i = tid; i < HP * RBP; i += 768) {
        (&h0buf[0][0])[i] = 0.0f;
        (&h1buf[0][0])[i] = 0.0f;
    }

    // this wave's 50-weight row (VGPR-resident; ~70 live regs/lane total)
    const float* wsrc = (w < 4) ? Whh0 : (w < 8) ? Wih1 : Whh1;
    DECLW(wW, wsrc + row * HH)
    PINW(wW)

    // L0 extras (valid addresses for every wave; used only by w<4)
    float4 w0v = ld4u(Wih0 + row * FF);
    const float bias0 = bih0[row] + bhh0[row];
    // L1 ew biases (used only by w>=8)
    const float bi = bih1[0 * HH + Um] + bhh1[0 * HH + Um];
    const float bf = bih1[1 * HH + Um] + bhh1[1 * HH + Um];
    const float bg = bih1[2 * HH + Um] + bhh1[2 * HH + Um];
    const float bo = bih1[3 * HH + Um] + bhh1[3 * HH + Um];

    const int rb = (w & 3) * 4;         // ew batch group for L0 (w<4) and L1-hh (w>=8)
    float c0a = 0.f, c0b = 0.f, c0c = 0.f, c0d = 0.f;   // layer-0 cell state (L0 waves)
    float c1a = 0.f, c1b = 0.f, c1c = 0.f, c1d = 0.f;   // layer-1 cell state (H1 waves)

    __syncthreads();

    // pipelined: iteration t computes h0(t) (L0 waves) and h1(t-1) (L1 waves)
    for (int t = 0; t <= TT; t++) {
        if (t < TT && (t & 63) == 0) {   // stage 64 timesteps of x, transposed [r][tl]
            {
                const int tl = tid & 63, r = tid >> 6;   // r in [0,12)
                xbufT[r][tl] = *(const float4*)(x + ((size_t)(b0 + r) * TT + (t + tl)) * FF);
            }
            if (tid < 256) {
                const int q = tid + 768, tl = q & 63, r = q >> 6;   // r in [12,16)
                xbufT[r][tl] = *(const float4*)(x + ((size_t)(b0 + r) * TT + (t + tl)) * FF);
            }
            __syncthreads();
        }
        const int tm = t & 63;

        // ---------------- phase 1: three matrix strips in parallel ----------------
        {
            float acc0, acc1, acc2, acc3, acc4, acc5, acc6, acc7;
            float acc8, acc9, acc10, acc11, acc12, acc13, acc14, acc15;
            if (w < 4) {
                if (t < TT) {   // layer-0 gates(t) from h0(t-1) + x(t)
                    XINIT(0, acc0)   XINIT(1, acc1)   XINIT(2, acc2)   XINIT(3, acc3)
                    XINIT(4, acc4)   XINIT(5, acc5)   XINIT(6, acc6)   XINIT(7, acc7)
                    XINIT(8, acc8)   XINIT(9, acc9)   XINIT(10, acc10) XINIT(11, acc11)
                    XINIT(12, acc12) XINIT(13, acc13) XINIT(14, acc14) XINIT(15, acc15)
                    JALL(wW, &h0buf[0][0])
                    if (w == 2) { STORE16(g0buf, w, tanh_f) } else { STORE16(g0buf, w, sigm) }
                }
            } else if (w < 8) {
                if (t >= 1) {   // pI(t-1) = Wih1 * h0(t-1)
                    acc0 = acc1 = acc2  = acc3  = acc4  = acc5  = acc6  = acc7  = 0.f;
                    acc8 = acc9 = acc10 = acc11 = acc12 = acc13 = acc14 = acc15 = 0.f;
                    JALL(wW, &h0buf[0][0])
                    STORE16(pIbuf, w - 4, idf)
                }
            } else {
                if (t >= 1) {   // pH(t-1) = Whh1 * h1(t-2)
                    acc0 = acc1 = acc2  = acc3  = acc4  = acc5  = acc6  = acc7  = 0.f;
                    acc8 = acc9 = acc10 = acc11 = acc12 = acc13 = acc14 = acc15 = 0.f;
                    JALL(wW, &h1buf[0][0])
                    STORE16(pHbuf, w - 8, idf)
                }
            }
        }
        __syncthreads();

        // ---------------- phase 2: elementwise updates ----------------
        if (w < 4) {
            if (t < TT) { EW0(0, c0a) EW0(1, c0b) EW0(2, c0c) EW0(3, c0d) }
        } else if (w >= 8) {
            if (t >= 1) { EW1(0, c1a) EW1(1, c1b) EW1(2, c1c) EW1(3, c1d) }
        }
        __syncthreads();
    }

    // ---------- final FC: out[b] = fcW @ h1(T-1) + fcb ----------
    if (tid < RB * FF) {
        const int r  = tid >> 2;
        const int ft = tid & 3;
        float s = fcb[ft];
        #pragma unroll
        for (int j = 0; j < HH; j++) s = fmaf(fcW[ft * HH + j], h1buf[j][r], s);
        out[(size_t)(b0 + r) * FF + ft] = s;
    }
}

extern "C" void kernel_launch(void* const* d_in, const int* in_sizes, int n_in,
                              void* d_out, int out_size, void* d_ws, size_t ws_size,
                              hipStream_t stream) {
    const float* x    = (const float*)d_in[0];
    const float* Wih0 = (const float*)d_in[1];
    const float* Whh0 = (const float*)d_in[2];
    const float* bih0 = (const float*)d_in[3];
    const float* bhh0 = (const float*)d_in[4];
    const float* Wih1 = (const float*)d_in[5];
    const float* Whh1 = (const float*)d_in[6];
    const float* bih1 = (const float*)d_in[7];
    const float* bhh1 = (const float*)d_in[8];
    const float* fcW  = (const float*)d_in[9];
    const float* fcb  = (const float*)d_in[10];
    float* out = (float*)d_out;

    const int B = in_sizes[0] / (TT * FF);   // 4096
    lstm12_kernel<<<B / RB, 768, 0, stream>>>(x, Wih0, Whh0, bih0, bhh0,
                                              Wih1, Whh1, bih1, bhh1, fcW, fcb, out);
}

// Round 7
// 1322.554 us; speedup vs baseline: 3.6815x; 3.6815x over previous
//
#include <hip/hip_runtime.h>

#define HH  50    // hidden size
#define RB  16    // batch elements per block (= MFMA M)
#define TT  512   // timesteps
#define FF  4     // input features
#define NT  14    // N-tiles of 16 rows (224 >= 200 gate rows)
#define PA  136   // hA pitch in u16 (k-dim 128 + pad, 16B-aligned rows)
#define PG  20    // gbuf pitch in dwords (r-dim 16 + pad, 16B-aligned)
#define NTH 896   // 14 waves

typedef __attribute__((ext_vector_type(8))) short bf16x8;   // 8 bf16 = 4 VGPRs
typedef __attribute__((ext_vector_type(4))) float f32x4;    // MFMA accumulator

__device__ __forceinline__ float sigm(float x)   { return 1.0f / (1.0f + __expf(-x)); }
__device__ __forceinline__ float tanh_f(float x) { return 1.0f - 2.0f / (1.0f + __expf(2.0f * x)); }

__device__ __forceinline__ unsigned short f2bf(float f) {   // RNE fp32->bf16 bits
    unsigned u = __float_as_uint(f);
    u += 0x7FFFu + ((u >> 16) & 1u);
    return (unsigned short)(u >> 16);
}
__device__ __forceinline__ float bf2f(unsigned short s) {
    return __uint_as_float(((unsigned)s) << 16);
}

// weight element for (job, row, k):  job0 = L0 [Wih0(4) | Whh0(50)],
// job1 = L1-ih [0(4) | Wih1(50)] (shares A with job0), job2 = L1-hh [Whh1(50)]
template<int JOB>
__device__ __forceinline__ float wsrc(int row, int k,
    const float* Wih0, const float* Whh0, const float* Wih1, const float* Whh1) {
    if (row >= 4 * HH) return 0.0f;
    if (JOB == 0) {
        if (k < FF) return Wih0[row * FF + k];
        if (k < FF + HH) return Whh0[row * HH + (k - FF)];
        return 0.0f;
    } else if (JOB == 1) {
        if (k >= FF && k < FF + HH) return Wih1[row * HH + (k - FF)];
        return 0.0f;
    } else {
        return (k < HH) ? Whh1[row * HH + k] : 0.0f;
    }
}

template<int JOB>
__device__ __forceinline__ void build_pair(bf16x8& hi, bf16x8& lo, int row, int kbase,
    const float* Wih0, const float* Whh0, const float* Wih1, const float* Whh1) {
    #pragma unroll
    for (int ii = 0; ii < 8; ++ii) {
        float wv = wsrc<JOB>(row, kbase + ii, Wih0, Whh0, Wih1, Whh1);
        unsigned short hb = f2bf(wv);
        hi[ii] = (short)hb;
        lo[ii] = (short)f2bf(wv - bf2f(hb));
    }
}

#define MFMA(a, b, c) __builtin_amdgcn_mfma_f32_16x16x32_bf16(a, b, c, 0, 0, 0)

// one tile-job: K'=128 as [hh(64) | hl(64)] x B-sections [Wh, Wh, Wl] -> 6 MFMAs
#define RUN_JOB(BH0, BH1, BL0, BL1, A0_, A1_, A2_, A3_, DST) { \
    f32x4 acc = {0.f, 0.f, 0.f, 0.f}; \
    acc = MFMA(A0_, BH0, acc); \
    acc = MFMA(A1_, BH1, acc); \
    acc = MFMA(A2_, BH0, acc); \
    acc = MFMA(A3_, BH1, acc); \
    acc = MFMA(A0_, BL0, acc); \
    acc = MFMA(A1_, BL1, acc); \
    if (rowOK) *(f32x4*)&DST[ddw] = acc; }

// layer-0 elementwise, one batch r = rbase+RR (component CC of the float4 reads)
#define EW0C(CC, RR, C) { \
    float ii_ = sigm(vi.CC + Bi0), ff_ = sigm(vf.CC + Bf0); \
    float gg_ = tanh_f(vg.CC + Bg0), oo_ = sigm(vo.CC + Bo0); \
    C = fmaf(ff_, C, ii_ * gg_); \
    float h_ = oo_ * tanh_f(C); \
    unsigned short hb_ = f2bf(h_); \
    hA0[(rbase + RR) * PA + FF + unit]      = hb_; \
    hA0[(rbase + RR) * PA + 64 + FF + unit] = f2bf(h_ - bf2f(hb_)); }

// layer-1 elementwise: combine ih+hh partials, write h1 splits (+ fp32 copy at end)
#define EW1C(CC, RR, C) { \
    float ii_ = sigm(via.CC + vib.CC + Bi1), ff_ = sigm(vfa.CC + vfb.CC + Bf1); \
    float gg_ = tanh_f(vga.CC + vgb.CC + Bg1), oo_ = sigm(voa.CC + vob.CC + Bo1); \
    C = fmaf(ff_, C, ii_ * gg_); \
    float h_ = oo_ * tanh_f(C); \
    unsigned short hb_ = f2bf(h_); \
    hA1[(rbase + RR) * PA + unit]      = hb_; \
    hA1[(rbase + RR) * PA + 64 + unit] = f2bf(h_ - bf2f(hb_)); \
    if (i == TT) h1f[unit * 16 + (rbase + RR)] = h_; }

__launch_bounds__(NTH)
__global__ void lstm_mfma_kernel(const float* __restrict__ x,
                                 const float* __restrict__ Wih0, const float* __restrict__ Whh0,
                                 const float* __restrict__ bih0, const float* __restrict__ bhh0,
                                 const float* __restrict__ Wih1, const float* __restrict__ Whh1,
                                 const float* __restrict__ bih1, const float* __restrict__ bhh1,
                                 const float* __restrict__ fcW,  const float* __restrict__ fcb,
                                 float* __restrict__ out)
{
    // A-operand buffers: h as bf16 split pairs, layout [r(16)][k(128+pad)]
    __shared__ __align__(16) unsigned short hA0[16 * PA];   // [x(4) h0h(50) | x_l h0l]
    __shared__ __align__(16) unsigned short hA1[16 * PA];   // [h1h(50) | h1l(50)]
    // gate pre-activations (MFMA D), layout [row(224)][r(16+pad)]
    __shared__ __align__(16) float gbuf0[224 * PG];
    __shared__ __align__(16) float gbuf1a[224 * PG];
    __shared__ __align__(16) float gbuf1b[224 * PG];
    __shared__ __align__(16) float xch[64 * 16 * 4];        // 64-step x chunk [slot][r][f]
    __shared__ float h1f[HH * 16];                          // final h1, fp32

    const int tid  = threadIdx.x;
    const int w    = tid >> 6;          // wave id: tile owner 0..13
    const int lane = tid & 63;
    const int b0   = blockIdx.x * RB;

    const int mrow  = lane & 15;        // n within tile
    const int qk    = lane >> 4;        // k-quad
    const int qk8   = qk * 8;
    const int row_n = w * 16 + mrow;    // global gate row (0..223)
    const bool rowOK = row_n < 4 * HH;
    const int ddw   = row_n * PG + qk * 4;   // D-store dword offset

    // ---- B-fragments (weights), register-resident for all 512 steps ----
    bf16x8 B0h0, B0h1, B0l0, B0l1;      // L0
    bf16x8 B1h0, B1h1, B1l0, B1l1;      // L1-ih
    bf16x8 B2h0, B2h1, B2l0, B2l1;      // L1-hh
    build_pair<0>(B0h0, B0l0, row_n, 0  + qk8, Wih0, Whh0, Wih1, Whh1);
    build_pair<0>(B0h1, B0l1, row_n, 32 + qk8, Wih0, Whh0, Wih1, Whh1);
    build_pair<1>(B1h0, B1l0, row_n, 0  + qk8, Wih0, Whh0, Wih1, Whh1);
    build_pair<1>(B1h1, B1l1, row_n, 32 + qk8, Wih0, Whh0, Wih1, Whh1);
    build_pair<2>(B2h0, B2l0, row_n, 0  + qk8, Wih0, Whh0, Wih1, Whh1);
    build_pair<2>(B2h1, B2l1, row_n, 32 + qk8, Wih0, Whh0, Wih1, Whh1);

    // ---- ew-role constants ----
    const int unit  = lane;                          // hidden unit (ew waves, lane<50)
    const int unitm = (lane < HH) ? lane : HH - 1;
    const int rbase = (w & 3) * 4;                   // ew batch group
    const float Bi0 = bih0[0*HH + unitm] + bhh0[0*HH + unitm];
    const float Bf0 = bih0[1*HH + unitm] + bhh0[1*HH + unitm];
    const float Bg0 = bih0[2*HH + unitm] + bhh0[2*HH + unitm];
    const float Bo0 = bih0[3*HH + unitm] + bhh0[3*HH + unitm];
    const float Bi1 = bih1[0*HH + unitm] + bhh1[0*HH + unitm];
    const float Bf1 = bih1[1*HH + unitm] + bhh1[1*HH + unitm];
    const float Bg1 = bih1[2*HH + unitm] + bhh1[2*HH + unitm];
    const float Bo1 = bih1[3*HH + unitm] + bhh1[3*HH + unitm];
    float c0 = 0.f, c1 = 0.f, c2 = 0.f, c3 = 0.f;    // cell states (per ew role)

    // ---- init: zero h buffers, stage x(0) ----
    for (int idx = tid; idx < 16 * PA; idx += NTH) { hA0[idx] = 0; hA1[idx] = 0; }
    if (tid < 64) {
        const int r = tid & 15, kq = tid >> 4;
        const float xs = x[((size_t)(b0 + r) * TT) * FF + kq];
        const unsigned short hb = f2bf(xs);
        hA0[r * PA + kq]      = hb;
        hA0[r * PA + 64 + kq] = f2bf(xs - bf2f(hb));
    }
    __syncthreads();

    // iteration i: MFMA computes gates0(i) and gates1(i-1); ew produces h0(i), h1(i-1)
    for (int i = 0; i <= TT; ++i) {
        if ((i & 63) == 0) {            // stage x chunk [i+1, i+64] (consumed in phase B)
            for (int q = tid; q < 1024; q += NTH) {
                const int slot = q >> 4, r = q & 15;
                int t = i + 1 + slot; if (t > TT - 1) t = TT - 1;
                *(float4*)&xch[(slot * 16 + r) * 4] =
                    *(const float4*)(x + ((size_t)(b0 + r) * TT + t) * FF);
            }
        }

        // ---- phase A: A-frag loads + 18 MFMAs + D stores ----
        const int abase = mrow * PA + qk8;
        const bf16x8 A0 = *(const bf16x8*)&hA0[abase];
        const bf16x8 A1 = *(const bf16x8*)&hA0[abase + 32];
        const bf16x8 A2 = *(const bf16x8*)&hA0[abase + 64];
        const bf16x8 A3 = *(const bf16x8*)&hA0[abase + 96];
        const bf16x8 A4 = *(const bf16x8*)&hA1[abase];
        const bf16x8 A5 = *(const bf16x8*)&hA1[abase + 32];
        const bf16x8 A6 = *(const bf16x8*)&hA1[abase + 64];
        const bf16x8 A7 = *(const bf16x8*)&hA1[abase + 96];
        if (i < TT) { RUN_JOB(B0h0, B0h1, B0l0, B0l1, A0, A1, A2, A3, gbuf0) }
        if (i >= 1) {
            RUN_JOB(B1h0, B1h1, B1l0, B1l1, A0, A1, A2, A3, gbuf1a)
            RUN_JOB(B2h0, B2h1, B2l0, B2l1, A4, A5, A6, A7, gbuf1b)
        }
        __syncthreads();

        // ---- phase B: elementwise + h writeback ----
        if (w < 4) {
            if (i < TT && lane < HH) {
                const float4 vi = *(const float4*)&gbuf0[(0*HH + unit) * PG + rbase];
                const float4 vf = *(const float4*)&gbuf0[(1*HH + unit) * PG + rbase];
                const float4 vg = *(const float4*)&gbuf0[(2*HH + unit) * PG + rbase];
                const float4 vo = *(const float4*)&gbuf0[(3*HH + unit) * PG + rbase];
                EW0C(x, 0, c0) EW0C(y, 1, c1) EW0C(z, 2, c2) EW0C(w, 3, c3)
            }
        } else if (w < 8) {
            if (i >= 1 && lane < HH) {
                const float4 via = *(const float4*)&gbuf1a[(0*HH + unit) * PG + rbase];
                const float4 vfa = *(const float4*)&gbuf1a[(1*HH + unit) * PG + rbase];
                const float4 vga = *(const float4*)&gbuf1a[(2*HH + unit) * PG + rbase];
                const float4 voa = *(const float4*)&gbuf1a[(3*HH + unit) * PG + rbase];
                const float4 vib = *(const float4*)&gbuf1b[(0*HH + unit) * PG + rbase];
                const float4 vfb = *(const float4*)&gbuf1b[(1*HH + unit) * PG + rbase];
                const float4 vgb = *(const float4*)&gbuf1b[(2*HH + unit) * PG + rbase];
                const float4 vob = *(const float4*)&gbuf1b[(3*HH + unit) * PG + rbase];
                EW1C(x, 0, c0) EW1C(y, 1, c1) EW1C(z, 2, c2) EW1C(w, 3, c3)
            }
        } else if (w == 8) {
            if (i + 1 < TT) {           // write x(i+1) splits into hA0 for next iter
                const int r = lane & 15, kq = lane >> 4;
                const float xs = xch[((i & 63) * 16 + r) * 4 + kq];
                const unsigned short hb = f2bf(xs);
                hA0[r * PA + kq]      = hb;
                hA0[r * PA + 64 + kq] = f2bf(xs - bf2f(hb));
            }
        }
        __syncthreads();
    }

    // ---- final FC: out[b] = fcW @ h1(T-1) + fcb ----
    if (tid < RB * FF) {
        const int r = tid >> 2, ft = tid & 3;
        float s = fcb[ft];
        #pragma unroll
        for (int j = 0; j < HH; j++) s = fmaf(fcW[ft * HH + j], h1f[j * 16 + r], s);
        out[(size_t)(b0 + r) * FF + ft] = s;
    }
}

extern "C" void kernel_launch(void* const* d_in, const int* in_sizes, int n_in,
                              void* d_out, int out_size, void* d_ws, size_t ws_size,
                              hipStream_t stream) {
    const float* x    = (const float*)d_in[0];
    const float* Wih0 = (const float*)d_in[1];
    const float* Whh0 = (const float*)d_in[2];
    const float* bih0 = (const float*)d_in[3];
    const float* bhh0 = (const float*)d_in[4];
    const float* Wih1 = (const float*)d_in[5];
    const float* Whh1 = (const float*)d_in[6];
    const float* bih1 = (const float*)d_in[7];
    const float* bhh1 = (const float*)d_in[8];
    const float* fcW  = (const float*)d_in[9];
    const float* fcb  = (const float*)d_in[10];
    float* out = (float*)d_out;

    const int B = in_sizes[0] / (TT * FF);   // 4096
    lstm_mfma_kernel<<<B / RB, NTH, 0, stream>>>(x, Wih0, Whh0, bih0, bhh0,
                                                 Wih1, Whh1, bih1, bhh1, fcW, fcb, out);
}

// Round 8
// 1153.905 us; speedup vs baseline: 4.2196x; 1.1462x over previous
//
#include <hip/hip_runtime.h>

#define HH  50    // hidden size
#define RB  16    // batch elements per block (= MFMA M)
#define TT  512   // timesteps
#define FF  4     // input features
#define PA  136   // hA row pitch in u16 (K'=128 + pad; 272B = 16B-aligned, stride 68 dwords -> uniform banks)
#define NW  13    // MFMA/ew waves (13 tiles x 16 rows >= 200 permuted gate rows)
#define NTH ((NW + 1) * 64)   // 896: waves 0..12 compute, wave 13 streams x

typedef __attribute__((ext_vector_type(8))) short bf16x8;   // 8 bf16 = 4 VGPRs
typedef __attribute__((ext_vector_type(4))) float f32x4;    // MFMA accumulator

__device__ __forceinline__ float sigm(float x)   { return 1.0f / (1.0f + __expf(-x)); }
__device__ __forceinline__ float tanh_f(float x) { return 1.0f - 2.0f / (1.0f + __expf(2.0f * x)); }

__device__ __forceinline__ unsigned short f2bf(float f) {   // RNE fp32->bf16 bits
    unsigned u = __float_as_uint(f);
    u += 0x7FFFu + ((u >> 16) & 1u);
    return (unsigned short)(u >> 16);
}
__device__ __forceinline__ float bf2f(unsigned short s) {
    return __uint_as_float(((unsigned)s) << 16);
}

// quad_perm DPP move (VALU pipe, no LDS): ctrl 0xB1 = lanes [1,0,3,2], 0x4E = [2,3,0,1]
template<int CTRL>
__device__ __forceinline__ float fdpp(float x) {
    return __int_as_float(__builtin_amdgcn_update_dpp(0, __float_as_int(x), CTRL, 0xF, 0xF, true));
}

// 4x4 transpose across quad lanes: out(lane j)[e] = in(lane e)[j]
__device__ __forceinline__ float4 qtr4(float4 x, bool l1, bool l2) {
    float t0 = fdpp<0xB1>(x.x), t1 = fdpp<0xB1>(x.y), t2 = fdpp<0xB1>(x.z), t3 = fdpp<0xB1>(x.w);
    float4 a;
    a.x = l1 ? t1 : x.x;
    a.y = l1 ? x.y : t0;
    a.z = l1 ? t3 : x.z;
    a.w = l1 ? x.w : t2;
    float u0 = fdpp<0x4E>(a.x), u1 = fdpp<0x4E>(a.y), u2 = fdpp<0x4E>(a.z), u3 = fdpp<0x4E>(a.w);
    float4 y;
    y.x = l2 ? u2 : a.x;
    y.y = l2 ? u3 : a.y;
    y.z = l2 ? a.z : u0;
    y.w = l2 ? a.w : u1;
    return y;
}

// split-bf16 B-frag for K' elements kb+0..7. K-layout: k'<4 -> Wx (x slots),
// 4<=k'<54 -> Wm (h slots), else 0. (hA1 has zeros in x slots -> pass Wx=null.)
__device__ __forceinline__ void buildB(bf16x8& bh, bf16x8& bl,
    const float* Wx, const float* Wm, int row_o, bool rok, int kb) {
    #pragma unroll
    for (int ii = 0; ii < 8; ++ii) {
        const int k = kb + ii;
        float wv = 0.0f;
        if (rok) {
            if (k < FF) { if (Wx) wv = Wx[row_o * FF + k]; }
            else if (k < FF + HH) wv = Wm[row_o * HH + (k - FF)];
        }
        const unsigned short hb = f2bf(wv);
        bh[ii] = (short)hb;
        bl[ii] = (short)f2bf(wv - bf2f(hb));
    }
}

#define MFMA(a, b, c) __builtin_amdgcn_mfma_f32_16x16x32_bf16(a, b, c, 0, 0, 0)
#define PINB(V) asm volatile("" : "+v"(V));

__launch_bounds__(NTH)
__global__ void lstm_v8(const float* __restrict__ x,
                        const float* __restrict__ Wih0, const float* __restrict__ Whh0,
                        const float* __restrict__ bih0, const float* __restrict__ bhh0,
                        const float* __restrict__ Wih1, const float* __restrict__ Whh1,
                        const float* __restrict__ bih1, const float* __restrict__ bhh1,
                        const float* __restrict__ fcW,  const float* __restrict__ fcb,
                        float* __restrict__ out)
{
    // ping-pong h buffers (split-bf16 A operands), K-layout [x(4) h_hi(50) .. | x_l(4) h_lo(50) ..]
    __shared__ __align__(16) unsigned short hA0[2][16 * PA];
    __shared__ __align__(16) unsigned short hA1[2][16 * PA];
    __shared__ float h1f[HH * 16];     // final h1 fp32 for FC

    const int tid  = threadIdx.x;
    const int w    = tid >> 6;
    const int lane = tid & 63;
    const int b0   = blockIdx.x * RB;

    const int n15 = lane & 15;
    const int qk  = lane >> 4;
    const int qk8 = qk * 8;
    const int jj  = lane & 3;
    const int uu  = (lane >> 2) & 3;
    const int m   = qk * 4 + jj;                 // ew batch
    const int u   = w * 4 + uu;                  // ew unit
    const bool uvalid = (w < NW) && (u < HH);
    const int um  = uvalid ? u : 0;

    // permuted gate row: row' = unit*4 + gate  ->  tile w holds units 4w..4w+3, all 4 gates
    const int rowp  = w * 16 + n15;
    const int gidx  = rowp & 3;
    const int runit = rowp >> 2;
    const bool rok  = (w < NW) && (runit < HH);
    const int row_o = rok ? gidx * HH + runit : 0;     // original row g*50+u

    for (int idx = tid; idx < 16 * PA; idx += NTH) {
        hA0[0][idx] = 0; hA0[1][idx] = 0;
        hA1[0][idx] = 0; hA1[1][idx] = 0;
    }

    // ---- B-frags: 12 register-resident split-bf16 fragments ----
    bf16x8 B0h0, B0h1, B0l0, B0l1, B1h0, B1h1, B1l0, B1l1, B2h0, B2h1, B2l0, B2l1;
    buildB(B0h0, B0l0, Wih0, Whh0, row_o, rok, qk8);        // L0: [Wih0 | Whh0]
    buildB(B0h1, B0l1, Wih0, Whh0, row_o, rok, 32 + qk8);
    buildB(B1h0, B1l0, nullptr, Wih1, row_o, rok, qk8);     // L1-ih (vs h0)
    buildB(B1h1, B1l1, nullptr, Wih1, row_o, rok, 32 + qk8);
    buildB(B2h0, B2l0, nullptr, Whh1, row_o, rok, qk8);     // L1-hh (vs h1)
    buildB(B2h1, B2l1, nullptr, Whh1, row_o, rok, 32 + qk8);
    PINB(B0h0) PINB(B0h1) PINB(B0l0) PINB(B0l1)
    PINB(B1h0) PINB(B1h1) PINB(B1l0) PINB(B1l1)
    PINB(B2h0) PINB(B2h1) PINB(B2l0) PINB(B2l1)

    // ew biases (per this lane's unit)
    const float b0i = bih0[0*HH + um] + bhh0[0*HH + um];
    const float b0f = bih0[1*HH + um] + bhh0[1*HH + um];
    const float b0g = bih0[2*HH + um] + bhh0[2*HH + um];
    const float b0o = bih0[3*HH + um] + bhh0[3*HH + um];
    const float b1i = bih1[0*HH + um] + bhh1[0*HH + um];
    const float b1f = bih1[1*HH + um] + bhh1[1*HH + um];
    const float b1g = bih1[2*HH + um] + bhh1[2*HH + um];
    const float b1o = bih1[3*HH + um] + bhh1[3*HH + um];

    // wave-13 x prefetch registers (1-iter latency slack)
    const int xm = lane >> 2, xk = lane & 3;
    float xcur = 0.f, xnxt = 0.f;
    if (w == NW) {
        xcur = x[((size_t)(b0 + xm) * TT + 1) * FF + xk];
        xnxt = x[((size_t)(b0 + xm) * TT + 2) * FF + xk];
    }

    __syncthreads();

    // x(0) into parity-0 buffer
    if (w == 0) {
        const float xv = x[((size_t)(b0 + xm) * TT + 0) * FF + xk];
        const unsigned short hb = f2bf(xv);
        hA0[0][xm * PA + xk]      = hb;
        hA0[0][xm * PA + 64 + xk] = f2bf(xv - bf2f(hb));
    }
    __syncthreads();

    float c0 = 0.f, c1 = 0.f;
    const bool l1b = (lane & 1) != 0, l2b = (lane & 2) != 0;

    // iter i: gates0(i) from [x(i),h0(i-1)]; gates1(i-1) from h0(i-1),h1(i-2). ONE barrier.
    for (int i = 0; i <= TT; ++i) {
        const int rb = i & 1, wb = (i + 1) & 1;

        if (w < NW) {
            const int ab = n15 * PA + qk8;
            const bf16x8 A0 = *(const bf16x8*)&hA0[rb][ab];
            const bf16x8 A1 = *(const bf16x8*)&hA0[rb][ab + 32];
            const bf16x8 A2 = *(const bf16x8*)&hA0[rb][ab + 64];
            const bf16x8 A3 = *(const bf16x8*)&hA0[rb][ab + 96];
            const bf16x8 A4 = *(const bf16x8*)&hA1[rb][ab];
            const bf16x8 A5 = *(const bf16x8*)&hA1[rb][ab + 32];
            const bf16x8 A6 = *(const bf16x8*)&hA1[rb][ab + 64];
            const bf16x8 A7 = *(const bf16x8*)&hA1[rb][ab + 96];

            if (i < TT) {   // ---- layer 0: MFMA + in-quad transpose + ew ----
                f32x4 a = {0.f, 0.f, 0.f, 0.f};
                a = MFMA(A0, B0h0, a); a = MFMA(A1, B0h1, a);   // Wh . h_hi
                a = MFMA(A2, B0h0, a); a = MFMA(A3, B0h1, a);   // Wh . h_lo
                a = MFMA(A0, B0l0, a); a = MFMA(A1, B0l1, a);   // Wl . h_hi
                const float4 y = qtr4(make_float4(a[0], a[1], a[2], a[3]), l1b, l2b);
                if (uvalid) {
                    const float gi = sigm(y.x + b0i), gf = sigm(y.y + b0f);
                    const float gc = tanh_f(y.z + b0g), go = sigm(y.w + b0o);
                    c0 = fmaf(gf, c0, gi * gc);
                    const float h = go * tanh_f(c0);
                    const unsigned short hb = f2bf(h);
                    hA0[wb][m * PA + 4 + u]  = hb;
                    hA0[wb][m * PA + 68 + u] = f2bf(h - bf2f(hb));
                }
            }
            if (i >= 1) {   // ---- layer 1: ih+hh fused in one accumulator ----
                f32x4 a = {0.f, 0.f, 0.f, 0.f};
                a = MFMA(A0, B1h0, a); a = MFMA(A1, B1h1, a);
                a = MFMA(A2, B1h0, a); a = MFMA(A3, B1h1, a);
                a = MFMA(A0, B1l0, a); a = MFMA(A1, B1l1, a);
                a = MFMA(A4, B2h0, a); a = MFMA(A5, B2h1, a);
                a = MFMA(A6, B2h0, a); a = MFMA(A7, B2h1, a);
                a = MFMA(A4, B2l0, a); a = MFMA(A5, B2l1, a);
                const float4 y = qtr4(make_float4(a[0], a[1], a[2], a[3]), l1b, l2b);
                if (uvalid) {
                    const float gi = sigm(y.x + b1i), gf = sigm(y.y + b1f);
                    const float gc = tanh_f(y.z + b1g), go = sigm(y.w + b1o);
                    c1 = fmaf(gf, c1, gi * gc);
                    const float h = go * tanh_f(c1);
                    const unsigned short hb = f2bf(h);
                    hA1[wb][m * PA + 4 + u]  = hb;
                    hA1[wb][m * PA + 68 + u] = f2bf(h - bf2f(hb));
                    if (i == TT) h1f[u * 16 + m] = h;
                }
            }
        } else {
            // wave 13: publish x(i+1) into the WRITE buffer; prefetch x(i+3)
            if (i + 1 < TT) {
                const unsigned short hb = f2bf(xcur);
                hA0[wb][xm * PA + xk]      = hb;
                hA0[wb][xm * PA + 64 + xk] = f2bf(xcur - bf2f(hb));
            }
            xcur = xnxt;
            if (i + 3 < TT) xnxt = x[((size_t)(b0 + xm) * TT + (i + 3)) * FF + xk];
        }
        __syncthreads();
    }

    // ---- final FC: out[b] = fcW @ h1(T-1) + fcb ----
    if (tid < RB * FF) {
        const int r = tid >> 2, ft = tid & 3;
        float s = fcb[ft];
        #pragma unroll
        for (int j = 0; j < HH; j++) s = fmaf(fcW[ft * HH + j], h1f[j * 16 + r], s);
        out[(size_t)(b0 + r) * FF + ft] = s;
    }
}

extern "C" void kernel_launch(void* const* d_in, const int* in_sizes, int n_in,
                              void* d_out, int out_size, void* d_ws, size_t ws_size,
                              hipStream_t stream) {
    const float* x    = (const float*)d_in[0];
    const float* Wih0 = (const float*)d_in[1];
    const float* Whh0 = (const float*)d_in[2];
    const float* bih0 = (const float*)d_in[3];
    const float* bhh0 = (const float*)d_in[4];
    const float* Wih1 = (const float*)d_in[5];
    const float* Whh1 = (const float*)d_in[6];
    const float* bih1 = (const float*)d_in[7];
    const float* bhh1 = (const float*)d_in[8];
    const float* fcW  = (const float*)d_in[9];
    const float* fcb  = (const float*)d_in[10];
    float* out = (float*)d_out;

    const int B = in_sizes[0] / (TT * FF);   // 4096
    lstm_v8<<<B / RB, NTH, 0, stream>>>(x, Wih0, Whh0, bih0, bhh0,
                                        Wih1, Whh1, bih1, bhh1, fcW, fcb, out);
}

// Round 9
// 844.680 us; speedup vs baseline: 5.7643x; 1.3661x over previous
//
#include <hip/hip_runtime.h>

#define HH  50    // hidden size
#define RB  16    // batch elements per block (= MFMA M)
#define TT  512   // timesteps
#define FF  4     // input features
#define PA  136   // hA row pitch in u16 (K'=128 + pad)
#define NW  13    // MFMA/ew waves (13 tiles x 16 rows >= 200 permuted gate rows)
#define NTH ((NW + 1) * 64)   // 896: waves 0..12 compute, wave 13 streams x

typedef __attribute__((ext_vector_type(8))) short bf16x8;   // 8 bf16 = 4 VGPRs
typedef __attribute__((ext_vector_type(4))) float f32x4;    // MFMA accumulator

// fast sigmoid/tanh: v_exp + v_rcp (no fp32 divide expansion)
__device__ __forceinline__ float sigm(float x) {
    return __builtin_amdgcn_rcpf(1.0f + __expf(-x));
}
__device__ __forceinline__ float tanh_f(float x) {
    return fmaf(-2.0f, __builtin_amdgcn_rcpf(1.0f + __expf(2.0f * x)), 1.0f);
}

__device__ __forceinline__ unsigned short f2bf(float f) {   // RNE fp32->bf16 bits
    unsigned u = __float_as_uint(f);
    u += 0x7FFFu + ((u >> 16) & 1u);
    return (unsigned short)(u >> 16);
}
__device__ __forceinline__ float bf2f(unsigned short s) {
    return __uint_as_float(((unsigned)s) << 16);
}

// quad_perm DPP move (VALU pipe, no LDS): ctrl 0xB1 = lanes [1,0,3,2], 0x4E = [2,3,0,1]
template<int CTRL>
__device__ __forceinline__ float fdpp(float x) {
    return __int_as_float(__builtin_amdgcn_update_dpp(0, __float_as_int(x), CTRL, 0xF, 0xF, true));
}

// 4x4 transpose across quad lanes: out(lane j)[e] = in(lane e)[j]
__device__ __forceinline__ float4 qtr4(float4 x, bool l1, bool l2) {
    float t0 = fdpp<0xB1>(x.x), t1 = fdpp<0xB1>(x.y), t2 = fdpp<0xB1>(x.z), t3 = fdpp<0xB1>(x.w);
    float4 a;
    a.x = l1 ? t1 : x.x;
    a.y = l1 ? x.y : t0;
    a.z = l1 ? t3 : x.z;
    a.w = l1 ? x.w : t2;
    float u0 = fdpp<0x4E>(a.x), u1 = fdpp<0x4E>(a.y), u2 = fdpp<0x4E>(a.z), u3 = fdpp<0x4E>(a.w);
    float4 y;
    y.x = l2 ? u2 : a.x;
    y.y = l2 ? u3 : a.y;
    y.z = l2 ? a.z : u0;
    y.w = l2 ? a.w : u1;
    return y;
}

// split-bf16 B-frag for K' elements kb+0..7. K-layout: k'<4 -> Wx (x slots),
// 4<=k'<54 -> Wm (h slots), else 0.
__device__ __forceinline__ void buildB(bf16x8& bh, bf16x8& bl,
    const float* Wx, const float* Wm, int row_o, bool rok, int kb) {
    #pragma unroll
    for (int ii = 0; ii < 8; ++ii) {
        const int k = kb + ii;
        float wv = 0.0f;
        if (rok) {
            if (k < FF) { if (Wx) wv = Wx[row_o * FF + k]; }
            else if (k < FF + HH) wv = Wm[row_o * HH + (k - FF)];
        }
        const unsigned short hb = f2bf(wv);
        bh[ii] = (short)hb;
        bl[ii] = (short)f2bf(wv - bf2f(hb));
    }
}

#define MFMA(a, b, c) __builtin_amdgcn_mfma_f32_16x16x32_bf16(a, b, c, 0, 0, 0)
#define PINB(V) asm volatile("" : "+v"(V));

__attribute__((amdgpu_waves_per_eu(4, 4)))
__launch_bounds__(NTH)
__global__ void lstm_v9(const float* __restrict__ x,
                        const float* __restrict__ Wih0, const float* __restrict__ Whh0,
                        const float* __restrict__ bih0, const float* __restrict__ bhh0,
                        const float* __restrict__ Wih1, const float* __restrict__ Whh1,
                        const float* __restrict__ bih1, const float* __restrict__ bhh1,
                        const float* __restrict__ fcW,  const float* __restrict__ fcb,
                        float* __restrict__ out)
{
    // ping-pong h buffers (split-bf16 A operands), K-layout [x(4) h_hi(50) .. | x_l(4) h_lo(50) ..]
    __shared__ __align__(16) unsigned short hA0[2][16 * PA];
    __shared__ __align__(16) unsigned short hA1[2][16 * PA];
    __shared__ float h1f[HH * 16];     // final h1 fp32 for FC

    const int tid  = threadIdx.x;
    const int w    = tid >> 6;
    const int lane = tid & 63;
    const int b0   = blockIdx.x * RB;

    const int n15 = lane & 15;
    const int qk  = lane >> 4;
    const int qk8 = qk * 8;
    const int jj  = lane & 3;
    const int uu  = (lane >> 2) & 3;
    const int m   = qk * 4 + jj;                 // ew batch
    const int u   = w * 4 + uu;                  // ew unit
    const bool uvalid = (w < NW) && (u < HH);
    const int um  = uvalid ? u : 0;

    // permuted gate row: row' = unit*4 + gate  ->  tile w holds units 4w..4w+3, all 4 gates
    const int rowp  = w * 16 + n15;
    const int gidx  = rowp & 3;
    const int runit = rowp >> 2;
    const bool rok  = (w < NW) && (runit < HH);
    const int row_o = rok ? gidx * HH + runit : 0;     // original row g*50+u

    for (int idx = tid; idx < 16 * PA; idx += NTH) {
        hA0[0][idx] = 0; hA0[1][idx] = 0;
        hA1[0][idx] = 0; hA1[1][idx] = 0;
    }

    // ---- B-frags: 12 register-resident split-bf16 fragments ----
    bf16x8 B0h0, B0h1, B0l0, B0l1, B1h0, B1h1, B1l0, B1l1, B2h0, B2h1, B2l0, B2l1;
    buildB(B0h0, B0l0, Wih0, Whh0, row_o, rok, qk8);        // L0: [Wih0 | Whh0]
    buildB(B0h1, B0l1, Wih0, Whh0, row_o, rok, 32 + qk8);
    buildB(B1h0, B1l0, nullptr, Wih1, row_o, rok, qk8);     // L1-ih (vs h0)
    buildB(B1h1, B1l1, nullptr, Wih1, row_o, rok, 32 + qk8);
    buildB(B2h0, B2l0, nullptr, Whh1, row_o, rok, qk8);     // L1-hh (vs h1)
    buildB(B2h1, B2l1, nullptr, Whh1, row_o, rok, 32 + qk8);
    PINB(B0h0) PINB(B0h1) PINB(B0l0) PINB(B0l1)
    PINB(B1h0) PINB(B1h1) PINB(B1l0) PINB(B1l1)
    PINB(B2h0) PINB(B2h1) PINB(B2l0) PINB(B2l1)

    // ew biases (per this lane's unit)
    const float b0i = bih0[0*HH + um] + bhh0[0*HH + um];
    const float b0f = bih0[1*HH + um] + bhh0[1*HH + um];
    const float b0g = bih0[2*HH + um] + bhh0[2*HH + um];
    const float b0o = bih0[3*HH + um] + bhh0[3*HH + um];
    const float b1i = bih1[0*HH + um] + bhh1[0*HH + um];
    const float b1f = bih1[1*HH + um] + bhh1[1*HH + um];
    const float b1g = bih1[2*HH + um] + bhh1[2*HH + um];
    const float b1o = bih1[3*HH + um] + bhh1[3*HH + um];

    // wave-13 x prefetch registers (1-iter latency slack)
    const int xm = lane >> 2, xk = lane & 3;
    float xcur = 0.f, xnxt = 0.f;
    if (w == NW) {
        xcur = x[((size_t)(b0 + xm) * TT + 1) * FF + xk];
        xnxt = x[((size_t)(b0 + xm) * TT + 2) * FF + xk];
    }

    __syncthreads();

    // x(0) into parity-0 buffer
    if (w == 0) {
        const float xv = x[((size_t)(b0 + xm) * TT + 0) * FF + xk];
        const unsigned short hb = f2bf(xv);
        hA0[0][xm * PA + xk]      = hb;
        hA0[0][xm * PA + 64 + xk] = f2bf(xv - bf2f(hb));
    }
    __syncthreads();

    float c0 = 0.f, c1 = 0.f;
    const bool l1b = (lane & 1) != 0, l2b = (lane & 2) != 0;

    // iter i: gates0(i) from [x(i),h0(i-1)]; gates1(i-1) from h0(i-1),h1(i-2). ONE barrier.
    for (int i = 0; i <= TT; ++i) {
        const int rb = i & 1, wb = (i + 1) & 1;

        if (w < NW) {
            const int ab = n15 * PA + qk8;
            const bf16x8 A0 = *(const bf16x8*)&hA0[rb][ab];
            const bf16x8 A1 = *(const bf16x8*)&hA0[rb][ab + 32];
            const bf16x8 A2 = *(const bf16x8*)&hA0[rb][ab + 64];
            const bf16x8 A3 = *(const bf16x8*)&hA0[rb][ab + 96];
            const bf16x8 A4 = *(const bf16x8*)&hA1[rb][ab];
            const bf16x8 A5 = *(const bf16x8*)&hA1[rb][ab + 32];
            const bf16x8 A6 = *(const bf16x8*)&hA1[rb][ab + 64];
            const bf16x8 A7 = *(const bf16x8*)&hA1[rb][ab + 96];

            if (i < TT) {   // ---- layer 0: two parallel 3-chains + combine ----
                f32x4 a = {0.f, 0.f, 0.f, 0.f}, a2 = {0.f, 0.f, 0.f, 0.f};
                a  = MFMA(A0, B0h0, a);  a  = MFMA(A1, B0h1, a);  a  = MFMA(A2, B0h0, a);
                a2 = MFMA(A3, B0h1, a2); a2 = MFMA(A0, B0l0, a2); a2 = MFMA(A1, B0l1, a2);
                const float4 y = qtr4(make_float4(a[0] + a2[0], a[1] + a2[1],
                                                  a[2] + a2[2], a[3] + a2[3]), l1b, l2b);
                if (uvalid) {
                    const float gi = sigm(y.x + b0i), gf = sigm(y.y + b0f);
                    const float gc = tanh_f(y.z + b0g), go = sigm(y.w + b0o);
                    c0 = fmaf(gf, c0, gi * gc);
                    const float h = go * tanh_f(c0);
                    const unsigned short hb = f2bf(h);
                    hA0[wb][m * PA + 4 + u]  = hb;
                    hA0[wb][m * PA + 68 + u] = f2bf(h - bf2f(hb));
                }
            }
            if (i >= 1) {   // ---- layer 1: ih-chain and hh-chain in parallel ----
                f32x4 p = {0.f, 0.f, 0.f, 0.f}, q = {0.f, 0.f, 0.f, 0.f};
                p = MFMA(A0, B1h0, p); p = MFMA(A1, B1h1, p); p = MFMA(A2, B1h0, p);
                p = MFMA(A3, B1h1, p); p = MFMA(A0, B1l0, p); p = MFMA(A1, B1l1, p);
                q = MFMA(A4, B2h0, q); q = MFMA(A5, B2h1, q); q = MFMA(A6, B2h0, q);
                q = MFMA(A7, B2h1, q); q = MFMA(A4, B2l0, q); q = MFMA(A5, B2l1, q);
                const float4 y = qtr4(make_float4(p[0] + q[0], p[1] + q[1],
                                                  p[2] + q[2], p[3] + q[3]), l1b, l2b);
                if (uvalid) {
                    const float gi = sigm(y.x + b1i), gf = sigm(y.y + b1f);
                    const float gc = tanh_f(y.z + b1g), go = sigm(y.w + b1o);
                    c1 = fmaf(gf, c1, gi * gc);
                    const float h = go * tanh_f(c1);
                    const unsigned short hb = f2bf(h);
                    hA1[wb][m * PA + 4 + u]  = hb;
                    hA1[wb][m * PA + 68 + u] = f2bf(h - bf2f(hb));
                    if (i == TT) h1f[u * 16 + m] = h;
                }
            }
        } else {
            // wave 13: publish x(i+1) into the WRITE buffer; prefetch x(i+3)
            if (i + 1 < TT) {
                const unsigned short hb = f2bf(xcur);
                hA0[wb][xm * PA + xk]      = hb;
                hA0[wb][xm * PA + 64 + xk] = f2bf(xcur - bf2f(hb));
            }
            xcur = xnxt;
            if (i + 3 < TT) xnxt = x[((size_t)(b0 + xm) * TT + (i + 3)) * FF + xk];
        }
        __syncthreads();
    }

    // ---- final FC: out[b] = fcW @ h1(T-1) + fcb ----
    if (tid < RB * FF) {
        const int r = tid >> 2, ft = tid & 3;
        float s = fcb[ft];
        #pragma unroll
        for (int j = 0; j < HH; j++) s = fmaf(fcW[ft * HH + j], h1f[j * 16 + r], s);
        out[(size_t)(b0 + r) * FF + ft] = s;
    }
}

extern "C" void kernel_launch(void* const* d_in, const int* in_sizes, int n_in,
                              void* d_out, int out_size, void* d_ws, size_t ws_size,
                              hipStream_t stream) {
    const float* x    = (const float*)d_in[0];
    const float* Wih0 = (const float*)d_in[1];
    const float* Whh0 = (const float*)d_in[2];
    const float* bih0 = (const float*)d_in[3];
    const float* bhh0 = (const float*)d_in[4];
    const float* Wih1 = (const float*)d_in[5];
    const float* Whh1 = (const float*)d_in[6];
    const float* bih1 = (const float*)d_in[7];
    const float* bhh1 = (const float*)d_in[8];
    const float* fcW  = (const float*)d_in[9];
    const float* fcb  = (const float*)d_in[10];
    float* out = (float*)d_out;

    const int B = in_sizes[0] / (TT * FF);   // 4096
    lstm_v9<<<B / RB, NTH, 0, stream>>>(x, Wih0, Whh0, bih0, bhh0,
                                        Wih1, Whh1, bih1, bhh1, fcW, fcb, out);
}

// Round 10
// 671.025 us; speedup vs baseline: 7.2560x; 1.2588x over previous
//
#include <hip/hip_runtime.h>

#define HH  50    // hidden size
#define RB  16    // batch elements per block (= MFMA N now)
#define TT  512   // timesteps
#define FF  4     // input features
#define PA  136   // hA row pitch in u16 (K'=128 + pad)
#define NW  13    // MFMA/ew waves (13 tiles x 16 rows >= 200 permuted gate rows)
#define NTH ((NW + 1) * 64)   // 896: waves 0..12 compute, wave 13 streams x

typedef __attribute__((ext_vector_type(8))) short bf16x8;   // 8 bf16 = 4 VGPRs
typedef __attribute__((ext_vector_type(4))) float f32x4;    // MFMA accumulator

// fast sigmoid/tanh: v_exp + v_rcp (no fp32 divide expansion)
__device__ __forceinline__ float sigm(float x) {
    return __builtin_amdgcn_rcpf(1.0f + __expf(-x));
}
__device__ __forceinline__ float tanh_f(float x) {
    return fmaf(-2.0f, __builtin_amdgcn_rcpf(1.0f + __expf(2.0f * x)), 1.0f);
}

__device__ __forceinline__ unsigned short f2bf(float f) {   // RNE fp32->bf16 bits
    unsigned u = __float_as_uint(f);
    u += 0x7FFFu + ((u >> 16) & 1u);
    return (unsigned short)(u >> 16);
}
__device__ __forceinline__ float bf2f(unsigned short s) {
    return __uint_as_float(((unsigned)s) << 16);
}

// raw barrier: drains LDS ops (producer->consumer ordering) but NOT vmcnt --
// wave 13's in-flight x prefetch stays in flight across the barrier.
__device__ __forceinline__ void block_sync_lds() {
    asm volatile("s_waitcnt lgkmcnt(0)\n\ts_barrier" ::: "memory");
}

// split-bf16 W-frag (A operand) for K' elements kb+0..7. K-layout: k'<4 -> Wx,
// 4<=k'<54 -> Wm, else 0.
__device__ __forceinline__ void buildB(bf16x8& bh, bf16x8& bl,
    const float* Wx, const float* Wm, int row_o, bool rok, int kb) {
    #pragma unroll
    for (int ii = 0; ii < 8; ++ii) {
        const int k = kb + ii;
        float wv = 0.0f;
        if (rok) {
            if (k < FF) { if (Wx) wv = Wx[row_o * FF + k]; }
            else if (k < FF + HH) wv = Wm[row_o * HH + (k - FF)];
        }
        const unsigned short hb = f2bf(wv);
        bh[ii] = (short)hb;
        bl[ii] = (short)f2bf(wv - bf2f(hb));
    }
}

#define MFMA(a, b, c) __builtin_amdgcn_mfma_f32_16x16x32_bf16(a, b, c, 0, 0, 0)
#define PINB(V) asm volatile("" : "+v"(V));

__attribute__((amdgpu_waves_per_eu(4, 4)))
__launch_bounds__(NTH)
__global__ void lstm_v10(const float* __restrict__ x,
                         const float* __restrict__ Wih0, const float* __restrict__ Whh0,
                         const float* __restrict__ bih0, const float* __restrict__ bhh0,
                         const float* __restrict__ Wih1, const float* __restrict__ Whh1,
                         const float* __restrict__ bih1, const float* __restrict__ bhh1,
                         const float* __restrict__ fcW,  const float* __restrict__ fcb,
                         float* __restrict__ out)
{
    // ping-pong h buffers (split-bf16 B operands), K-layout [x(4) h_hi(50) .. | x_l(4) h_lo(50) ..]
    __shared__ __align__(16) unsigned short hA0[2][16 * PA];
    __shared__ __align__(16) unsigned short hA1[2][16 * PA];
    __shared__ float h1f[HH * 16];     // final h1 fp32 for FC

    const int tid  = threadIdx.x;
    const int w    = tid >> 6;
    const int lane = tid & 63;
    const int b0   = blockIdx.x * RB;

    const int n15 = lane & 15;
    const int qk  = lane >> 4;
    const int qk8 = qk * 8;

    // D = W . h^T  =>  lane holds D[row'=qk*4+reg][batch=n15]:
    // with row' = 4*unit+gate, acc regs 0..3 = gates i,f,g,o of unit u for batch m.
    const int m = n15;                    // ew batch
    const int u = w * 4 + qk;             // ew unit
    const bool uvalid = (w < NW) && (u < HH);
    const int um = uvalid ? u : 0;

    // W-frag row (A operand M index): permuted row' = w*16 + n15
    const int rowp  = w * 16 + n15;
    const int gidx  = rowp & 3;
    const int runit = rowp >> 2;
    const bool rok  = (w < NW) && (runit < HH);
    const int row_o = rok ? gidx * HH + runit : 0;     // original row g*50+unit

    for (int idx = tid; idx < 16 * PA; idx += NTH) {
        hA0[0][idx] = 0; hA0[1][idx] = 0;
        hA1[0][idx] = 0; hA1[1][idx] = 0;
    }

    // ---- W-frags: 12 register-resident split-bf16 fragments (A operands) ----
    bf16x8 B0h0, B0h1, B0l0, B0l1, B1h0, B1h1, B1l0, B1l1, B2h0, B2h1, B2l0, B2l1;
    buildB(B0h0, B0l0, Wih0, Whh0, row_o, rok, qk8);        // L0: [Wih0 | Whh0]
    buildB(B0h1, B0l1, Wih0, Whh0, row_o, rok, 32 + qk8);
    buildB(B1h0, B1l0, nullptr, Wih1, row_o, rok, qk8);     // L1-ih (vs h0)
    buildB(B1h1, B1l1, nullptr, Wih1, row_o, rok, 32 + qk8);
    buildB(B2h0, B2l0, nullptr, Whh1, row_o, rok, qk8);     // L1-hh (vs h1)
    buildB(B2h1, B2l1, nullptr, Whh1, row_o, rok, 32 + qk8);
    PINB(B0h0) PINB(B0h1) PINB(B0l0) PINB(B0l1)
    PINB(B1h0) PINB(B1h1) PINB(B1l0) PINB(B1l1)
    PINB(B2h0) PINB(B2h1) PINB(B2l0) PINB(B2l1)

    // bias vectors preloaded into the MFMA C operand (gates of unit u)
    const float b0i = bih0[0*HH + um] + bhh0[0*HH + um];
    const float b0f = bih0[1*HH + um] + bhh0[1*HH + um];
    const float b0g = bih0[2*HH + um] + bhh0[2*HH + um];
    const float b0o = bih0[3*HH + um] + bhh0[3*HH + um];
    const float b1i = bih1[0*HH + um] + bhh1[0*HH + um];
    const float b1f = bih1[1*HH + um] + bhh1[1*HH + um];
    const float b1g = bih1[2*HH + um] + bhh1[2*HH + um];
    const float b1o = bih1[3*HH + um] + bhh1[3*HH + um];
    const f32x4 C0 = {b0i, b0f, b0g, b0o};
    const f32x4 C1 = {b1i, b1f, b1g, b1o};

    // wave-13 x prefetch registers (2-iter latency slack; vm never drains at barrier)
    const int xm = lane >> 2, xk = lane & 3;
    float xcur = 0.f, xnxt = 0.f;
    if (w == NW) {
        xcur = x[((size_t)(b0 + xm) * TT + 1) * FF + xk];
        xnxt = x[((size_t)(b0 + xm) * TT + 2) * FF + xk];
    }

    __syncthreads();

    // x(0) into parity-0 buffer
    if (w == 0) {
        const float xv = x[((size_t)(b0 + xm) * TT + 0) * FF + xk];
        const unsigned short hb = f2bf(xv);
        hA0[0][xm * PA + xk]      = hb;
        hA0[0][xm * PA + 64 + xk] = f2bf(xv - bf2f(hb));
    }
    __syncthreads();

    float c0 = 0.f, c1 = 0.f;

    // iter i: gates0(i) from [x(i),h0(i-1)]; gates1(i-1) from h0(i-1),h1(i-2). ONE barrier.
    for (int i = 0; i <= TT; ++i) {
        const int rb = i & 1, wb = (i + 1) & 1;

        if (w < NW) {
            const int ab = n15 * PA + qk8;
            const bf16x8 A0 = *(const bf16x8*)&hA0[rb][ab];
            const bf16x8 A1 = *(const bf16x8*)&hA0[rb][ab + 32];
            const bf16x8 A2 = *(const bf16x8*)&hA0[rb][ab + 64];
            const bf16x8 A3 = *(const bf16x8*)&hA0[rb][ab + 96];
            const bf16x8 A4 = *(const bf16x8*)&hA1[rb][ab];
            const bf16x8 A5 = *(const bf16x8*)&hA1[rb][ab + 32];
            const bf16x8 A6 = *(const bf16x8*)&hA1[rb][ab + 64];
            const bf16x8 A7 = *(const bf16x8*)&hA1[rb][ab + 96];

            if (i < TT) {   // ---- layer 0: two parallel 3-chains, bias in C ----
                f32x4 a = C0, a2 = {0.f, 0.f, 0.f, 0.f};
                a  = MFMA(B0h0, A0, a);  a  = MFMA(B0h1, A1, a);  a  = MFMA(B0h0, A2, a);
                a2 = MFMA(B0h1, A3, a2); a2 = MFMA(B0l0, A0, a2); a2 = MFMA(B0l1, A1, a2);
                if (uvalid) {
                    const float gi = sigm(a[0] + a2[0]);
                    const float gf = sigm(a[1] + a2[1]);
                    const float gc = tanh_f(a[2] + a2[2]);
                    const float go = sigm(a[3] + a2[3]);
                    c0 = fmaf(gf, c0, gi * gc);
                    const float h = go * tanh_f(c0);
                    const unsigned short hb = f2bf(h);
                    hA0[wb][m * PA + 4 + u]  = hb;
                    hA0[wb][m * PA + 68 + u] = f2bf(h - bf2f(hb));
                }
            }
            if (i >= 1) {   // ---- layer 1: ih-chain and hh-chain in parallel ----
                f32x4 p = C1, q = {0.f, 0.f, 0.f, 0.f};
                p = MFMA(B1h0, A0, p); p = MFMA(B1h1, A1, p); p = MFMA(B1h0, A2, p);
                p = MFMA(B1h1, A3, p); p = MFMA(B1l0, A0, p); p = MFMA(B1l1, A1, p);
                q = MFMA(B2h0, A4, q); q = MFMA(B2h1, A5, q); q = MFMA(B2h0, A6, q);
                q = MFMA(B2h1, A7, q); q = MFMA(B2l0, A4, q); q = MFMA(B2l1, A5, q);
                if (uvalid) {
                    const float gi = sigm(p[0] + q[0]);
                    const float gf = sigm(p[1] + q[1]);
                    const float gc = tanh_f(p[2] + q[2]);
                    const float go = sigm(p[3] + q[3]);
                    c1 = fmaf(gf, c1, gi * gc);
                    const float h = go * tanh_f(c1);
                    const unsigned short hb = f2bf(h);
                    hA1[wb][m * PA + 4 + u]  = hb;
                    hA1[wb][m * PA + 68 + u] = f2bf(h - bf2f(hb));
                    if (i == TT) h1f[u * 16 + m] = h;
                }
            }
        } else {
            // wave 13: issue next prefetch FIRST, then publish x(i+1) to write buffer
            float xnew = 0.f;
            if (i + 3 < TT) xnew = x[((size_t)(b0 + xm) * TT + (i + 3)) * FF + xk];
            if (i + 1 < TT) {
                const unsigned short hb = f2bf(xcur);
                hA0[wb][xm * PA + xk]      = hb;
                hA0[wb][xm * PA + 64 + xk] = f2bf(xcur - bf2f(hb));
            }
            xcur = xnxt;
            xnxt = xnew;
        }
        block_sync_lds();
    }

    __syncthreads();

    // ---- final FC: out[b] = fcW @ h1(T-1) + fcb ----
    if (tid < RB * FF) {
        const int r = tid >> 2, ft = tid & 3;
        float s = fcb[ft];
        #pragma unroll
        for (int j = 0; j < HH; j++) s = fmaf(fcW[ft * HH + j], h1f[j * 16 + r], s);
        out[(size_t)(b0 + r) * FF + ft] = s;
    }
}

extern "C" void kernel_launch(void* const* d_in, const int* in_sizes, int n_in,
                              void* d_out, int out_size, void* d_ws, size_t ws_size,
                              hipStream_t stream) {
    const float* x    = (const float*)d_in[0];
    const float* Wih0 = (const float*)d_in[1];
    const float* Whh0 = (const float*)d_in[2];
    const float* bih0 = (const float*)d_in[3];
    const float* bhh0 = (const float*)d_in[4];
    const float* Wih1 = (const float*)d_in[5];
    const float* Whh1 = (const float*)d_in[6];
    const float* bih1 = (const float*)d_in[7];
    const float* bhh1 = (const float*)d_in[8];
    const float* fcW  = (const float*)d_in[9];
    const float* fcb  = (const float*)d_in[10];
    float* out = (float*)d_out;

    const int B = in_sizes[0] / (TT * FF);   // 4096
    lstm_v10<<<B / RB, NTH, 0, stream>>>(x, Wih0, Whh0, bih0, bhh0,
                                         Wih1, Whh1, bih1, bhh1, fcW, fcb, out);
}